// Round 9
// baseline (2242.888 us; speedup 1.0000x reference)
//
#include <hip/hip_runtime.h>
#include <hip/hip_bf16.h>
#include <cstdint>
#include <cstddef>

// Problem dims
#define SS   512
#define BB   64
#define EMBD 512
#define HIDD 512
#define MAXD 1024
#define NCLS 20
#define KCAT 1536
#define ROWS (SS*BB)   // 32768

// ---------- small helpers ----------
__device__ __forceinline__ uint16_t f2bf(float f) {
  uint32_t u = __float_as_uint(f);
  uint32_t r = u + 0x7fffu + ((u >> 16) & 1u);
  return (uint16_t)(r >> 16);
}
__device__ __forceinline__ float bf2f(uint32_t h) {
  return __uint_as_float(h << 16);
}
__device__ __forceinline__ uint32_t pk2(float a, float b) {
  return (uint32_t)f2bf(a) | ((uint32_t)f2bf(b) << 16);
}

// fast tanh: (1-e^{-2|x|})/(1+e^{-2|x|}) with native exp2/rcp, sign restore.
__device__ __forceinline__ float fast_tanh(float x) {
  float ax = __builtin_fabsf(x);
  float e  = __builtin_amdgcn_exp2f(ax * -2.885390081777927f);  // e^{-2ax}
  float r  = (1.f - e) * __builtin_amdgcn_rcpf(1.f + e);
  return __builtin_copysignf(r, x);
}

typedef float v2f __attribute__((ext_vector_type(2)));

// expand a bf16-pair word into 2 f32 (low -> .x, high -> .y)
__device__ __forceinline__ v2f bfpair(uint32_t w) {
  v2f r;
  r.x = __uint_as_float(w << 16);
  r.y = __uint_as_float(w & 0xffff0000u);
  return r;
}

__device__ __forceinline__ void gl_lds16(const void* g, void* l) {
  __builtin_amdgcn_global_load_lds((const __attribute__((address_space(1))) void*)g,
                                   (__attribute__((address_space(3))) void*)l,
                                   16, 0, 0);
}

typedef short v8s __attribute__((ext_vector_type(8)));
typedef float v4f __attribute__((ext_vector_type(4)));

// ---------- K0: gather emb -> cat[:,512:1024] (bf16), convert weights to bf16 ----------
__global__ __launch_bounds__(256) void prep_kernel(
    const int* __restrict__ inp, const float* __restrict__ table,
    const float* __restrict__ Wsl, const float* __restrict__ Wsr,
    const float* __restrict__ Wl,  const float* __restrict__ Wr,
    const float* __restrict__ Wmax,
    uint16_t* __restrict__ cat, uint16_t* __restrict__ wslb,
    uint16_t* __restrict__ wsrb, uint16_t* __restrict__ wlb,
    uint16_t* __restrict__ wrb, uint16_t* __restrict__ wmaxb)
{
  const int blk = blockIdx.x, t = threadIdx.x;
  if (blk < 8192) {
    const int r = blk * 4 + (t >> 6);
    const int lane = t & 63;
    const int token = inp[r];
    const float4* src = (const float4*)(table + (size_t)token * EMBD);
    uint16_t* dst = cat + (size_t)r * KCAT + 512;
#pragma unroll
    for (int p = 0; p < 2; ++p) {
      const int slot = lane + 64 * p;   // 0..127 float4 slots per row
      float4 v = src[slot];
      uint2 o;
      o.x = pk2(v.x, v.y);
      o.y = pk2(v.z, v.w);
      *(uint2*)(dst + slot * 4) = o;
    }
  } else {
    size_t flat = (size_t)(blk - 8192) * 2048 + (size_t)t * 8;
    const float* src; uint16_t* dst; size_t off;
    if (flat < 262144)       { src = Wsl;  dst = wslb;  off = flat; }
    else if (flat < 524288)  { src = Wsr;  dst = wsrb;  off = flat - 262144; }
    else if (flat < 786432)  { src = Wl;   dst = wlb;   off = flat - 524288; }
    else if (flat < 1048576) { src = Wr;   dst = wrb;   off = flat - 786432; }
    else                     { src = Wmax; dst = wmaxb; off = flat - 1048576; }
    float4 v0 = *(const float4*)(src + off);
    float4 v1 = *(const float4*)(src + off + 4);
    uint4 o;
    o.x = pk2(v0.x, v0.y); o.y = pk2(v0.z, v0.w);
    o.z = pk2(v1.x, v1.y); o.w = pk2(v1.z, v1.w);
    *(uint4*)(dst + off) = o;
  }
}

// ---------- GEMM (m97-style): C[M x 1024] = A[M x K] @ W^T, 128x128 tiles, BK=64 ----------
// MODE 0: out = A@W^T + bias -> bf16 store (proj GEMM, W split at n=512)
// MODE 1: v = tanh(A@W^T + bias); partial[mb][b][n] = max over the block's 2 s-rows
template<int MODE>
__global__ __launch_bounds__(256, 2) void gemm_kernel(
    const uint16_t* __restrict__ A, int lda, int K,
    const uint16_t* __restrict__ W0, const uint16_t* __restrict__ W1,
    const float* __restrict__ bias0, const float* __restrict__ bias1,
    uint16_t* __restrict__ outb, float* __restrict__ partial)
{
  __shared__ unsigned char smem[32768];
  uint16_t* lA = (uint16_t*)smem;            // 128x64 bf16 = 16 KB
  uint16_t* lW = (uint16_t*)(smem + 16384);  // 128x64 bf16 = 16 KB

  const int tid = threadIdx.x;
  const int mb = blockIdx.x, nb = blockIdx.y;
  const int m0 = mb * 128, n0 = nb * 128;

  const uint16_t* Wp = W0;
  const float* biasp = bias0;
  int nr0 = n0;
  if (MODE == 0 && n0 >= 512) { Wp = W1; biasp = bias1; nr0 = n0 - 512; }

  const int w = tid >> 6, lane = tid & 63;
  const int mw = w & 1, nw = w >> 1;

  v4f acc[4][4];
#pragma unroll
  for (int i = 0; i < 4; ++i)
#pragma unroll
    for (int j = 0; j < 4; ++j) {
      v4f z = {0.f, 0.f, 0.f, 0.f};
      acc[i][j] = z;
    }

  const int r_st = tid >> 3;   // + p*32
  const int u_st = tid & 7;

  for (int kk = 0; kk < K; kk += 64) {
    __syncthreads();
#pragma unroll
    for (int p = 0; p < 4; ++p) {
      const int r = p * 32 + r_st;
      gl_lds16(A + (size_t)(m0 + r) * lda + kk + u_st * 8, lA + (p * 256 + tid) * 8);
    }
#pragma unroll
    for (int p = 0; p < 4; ++p) {
      const int r = p * 32 + r_st;
      gl_lds16(Wp + (size_t)(nr0 + r) * K + kk + u_st * 8, lW + (p * 256 + tid) * 8);
    }
    __syncthreads();
#pragma unroll
    for (int ks = 0; ks < 2; ++ks) {
      v8s af[4], wf[4];
#pragma unroll
      for (int i = 0; i < 4; ++i)
        af[i] = *(const v8s*)&lA[(mw * 64 + i * 16 + (lane & 15)) * 64 + ks * 32 + (lane >> 4) * 8];
#pragma unroll
      for (int j = 0; j < 4; ++j)
        wf[j] = *(const v8s*)&lW[(nw * 64 + j * 16 + (lane & 15)) * 64 + ks * 32 + (lane >> 4) * 8];
#pragma unroll
      for (int i = 0; i < 4; ++i)
#pragma unroll
        for (int j = 0; j < 4; ++j)
          acc[i][j] = __builtin_amdgcn_mfma_f32_16x16x32_bf16(af[i], wf[j], acc[i][j], 0, 0, 0);
    }
  }

  __syncthreads();  // all LDS frag reads done before epilogue reuse

  if (MODE == 0) {
#pragma unroll
    for (int i = 0; i < 4; ++i)
#pragma unroll
      for (int j = 0; j < 4; ++j) {
        const int nl = nw * 64 + j * 16 + (lane & 15);
        const float bv = biasp[nr0 + nl];
        const int colg = n0 + nl;
#pragma unroll
        for (int r = 0; r < 4; ++r) {
          const int rowg = m0 + mw * 64 + i * 16 + (lane >> 4) * 4 + r;
          outb[(size_t)rowg * 1024 + colg] = f2bf(acc[i][j][r] + bv);
        }
      }
  } else {
    float* lred = (float*)smem;   // 64 b x 128 n f32 = 32 KB
    if (mw == 1) {
#pragma unroll
      for (int i = 0; i < 4; ++i)
#pragma unroll
        for (int j = 0; j < 4; ++j) {
          const int nl = nw * 64 + j * 16 + (lane & 15);
          const float bv = biasp[nr0 + nl];
#pragma unroll
          for (int r = 0; r < 4; ++r) {
            const int bl = i * 16 + (lane >> 4) * 4 + r;
            lred[bl * 128 + nl] = fast_tanh(acc[i][j][r] + bv);
          }
        }
    }
    __syncthreads();
    if (mw == 0) {
#pragma unroll
      for (int i = 0; i < 4; ++i)
#pragma unroll
        for (int j = 0; j < 4; ++j) {
          const int nl = nw * 64 + j * 16 + (lane & 15);
          const float bv = biasp[nr0 + nl];
#pragma unroll
          for (int r = 0; r < 4; ++r) {
            const int bl = i * 16 + (lane >> 4) * 4 + r;
            const float v = fast_tanh(acc[i][j][r] + bv);
            partial[((size_t)mb * 64 + bl) * 1024 + n0 + nl] = fmaxf(v, lred[bl * 128 + nl]);
          }
        }
    }
  }
}

// ---------- K2: bidirectional recurrence (R3 structure) + packed-f32 dot ----------
// Base = R3's proven 643us kernel. R8's MFMA scan REVERTED (16 blocks, 4 serial
// poll chains/thread, row-aliasing LDS banks -> 1460us). Cycle model from the
// R4 A/B (+128 readlane -> +518 VALU cyc/step): dot2bf issues at 4 cyc/wave
// (half rate), so R3's dot = 1024 of its 3014 cyc step.
// ONLY change vs R3: the dot runs on full-rate packed f32 (v_pk_fma_f32,
// selected from __builtin_elementwise_fma on float2 -- CDNA4 packed-fp32):
//  * W expanded once to f32 pairs (wAp/wBp, 256 regs; parks in the unified
//    AGPR file like the bf16 version -- proven free R1-R4);
//  * cfull is f32[512] (2 KB); dot reads 32 wave-uniform b128 broadcasts;
//  * finalize writes its f32 pair to LDS + the SAME bf16 publish packet;
//  * remote polls convert bf16->f32 (2 shifts) before the LDS write.
// Exchange protocol, barriers, ee/cat pipelines byte-identical to R3:
// publish@i -> parity i&1, seq i+1; remote poll@i -> parity (i&1)^1, seq i;
// skew <=1; publisher and poller are different waves (no store/spin hazard).
__global__ __launch_bounds__(512, 1) void scan_kernel(
    const uint16_t* __restrict__ ee,     // [32768][1024] bf16: ls | rs
    const uint16_t* __restrict__ wlb, const uint16_t* __restrict__ wrb,
    const float* __restrict__ bl, const float* __restrict__ br,
    const float* __restrict__ cl0, const float* __restrict__ cr0,
    uint16_t* __restrict__ cat,
    uint64_t* __restrict__ cbuf)
{
  const int tid = threadIdx.x;
  const int bid = blockIdx.x;
  const int b    = bid & 63;
  const int d    = (bid >> 6) & 1;
  const int half = bid >> 7;          // h-half; partner differs only in bit 7

  // dot geometry: hp = row-pair within half (rows half*256+2hp, +1),
  // kq = 128-element k-window = 128 floats of cfullf.
  const int hp = tid & 127;
  const int kq = tid >> 7;            // wave-uniform
  const bool remote = (kq >> 1) != half;   // wave's k-window is the partner's half

  __shared__ __align__(16) float cfullf[512];     // full c (512 h) as f32
  __shared__ float2 part2[4 * 128];               // [kq][hp] = (rowEven, rowOdd)

  // ---- W rows into regs as f32 pairs (loop-invariant; 128 v2f = 256 regs) ----
  v2f wAp[64], wBp[64];
  {
    const uint16_t* wsrc = (d ? wrb : wlb) + (size_t)(half * 256 + 2 * hp) * HIDD + kq * 128;
    const uint4* pA = (const uint4*)wsrc;
    const uint4* pB = (const uint4*)(wsrc + HIDD);
#pragma unroll
    for (int j = 0; j < 16; ++j) {
      uint4 qa = pA[j], qb = pB[j];
      wAp[4 * j]     = bfpair(qa.x); wAp[4 * j + 1] = bfpair(qa.y);
      wAp[4 * j + 2] = bfpair(qa.z); wAp[4 * j + 3] = bfpair(qa.w);
      wBp[4 * j]     = bfpair(qb.x); wBp[4 * j + 1] = bfpair(qb.y);
      wBp[4 * j + 2] = bfpair(qb.z); wBp[4 * j + 3] = bfpair(qb.w);
    }
  }
  if (tid < 256) {
    const float* c0v = d ? cr0 : cl0;
    float2 cv = ((const float2*)c0v)[tid];
    cfullf[2 * tid] = cv.x; cfullf[2 * tid + 1] = cv.y;
  }

  // finalize lanes: 2 local waves -> tid in [half*256, half*256+128)
  const int fbase = half * 256;
  const unsigned ft = (unsigned)(tid - fbase);   // <128u => finalize lane
  const int fp = tid - fbase;

  float2 biasv = {0.f, 0.f};
  if (ft < 128u) {
    const float* bvec = d ? br : bl;
    biasv = ((const float2*)bvec)[half * 128 + fp];
  }
  __syncthreads();

  const size_t ecol = (size_t)(d * 512 + half * 256 + 2 * fp);
  const int fcol = (d ? 1024 : 0) + half * 256 + 2 * fp;   // cat column

  // remote poll geometry: partner publishes its h-pair j at slot j; this wave
  // needs pairs [kq*32 ... ) of the remote half: pslot covers the kq group.
  const int pslot = ((kq & 1) << 6) | (tid & 63);
  const int cword = ((1 - half) << 7) | pslot;    // pair index in cfullf
  const int pbid  = bid ^ 128;

  // 2-deep ee prefetch ring (finalize lanes)
  uint32_t ep0 = 0, ep1 = 0;
  if (ft < 128u) {
    const int s0i = d ? 511 : 0;
    const int s1i = d ? 510 : 1;
    ep0 = *(const uint32_t*)&ee[(size_t)(s0i * BB + b) * 1024 + ecol];
    ep1 = *(const uint32_t*)&ee[(size_t)(s1i * BB + b) * 1024 + ecol];
  }

  uint32_t prPrev = 0;
  int sPrev = -1;

  for (int i = 0; i < 512; ++i) {
    const int s = d ? (511 - i) : i;
    uint32_t ep2 = 0;
    if (ft < 128u) {
      const int i2 = (i + 2) & 511;
      const int s2 = d ? (511 - i2) : i2;
      ep2 = *(const uint32_t*)&ee[(size_t)(s2 * BB + b) * 1024 + ecol];
      // pipelined cat store from previous iteration (drains during the dot)
      if (sPrev >= 0)
        *(uint32_t*)&cat[(size_t)(sPrev * BB + b) * KCAT + fcol] = prPrev;
    }

    // remote waves: fetch the partner c-half pairs this wave's dot needs.
    // seq i was published by partner at its iter i-1 (parity (i&1)^1).
    if (remote && i != 0) {
      const uint64_t want = (uint64_t)(uint32_t)i;
      const uint64_t* slot = &cbuf[(size_t)(((((i & 1) ^ 1)) * 256 + pbid) * 128 + pslot)];
      uint64_t v = __hip_atomic_load(slot, __ATOMIC_RELAXED, __HIP_MEMORY_SCOPE_AGENT);
      while ((v >> 32) != want) {
        __builtin_amdgcn_s_sleep(1);
        v = __hip_atomic_load(slot, __ATOMIC_RELAXED, __HIP_MEMORY_SCOPE_AGENT);
      }
      const uint32_t pr = (uint32_t)v;
      float2 cw; cw.x = bf2f(pr & 0xffffu); cw.y = bf2f(pr >> 16);
      *(float2*)&cfullf[2 * cword] = cw;
      // wave-local: our 64 lanes wrote exactly the pairs we are about to read.
      asm volatile("s_waitcnt lgkmcnt(0)" ::: "memory");
    }

    // dot: rows half*256+2hp/+1, k-window [kq*128,+128). W in regs as f32
    // pairs; c via wave-uniform float4 broadcasts; v_pk_fma_f32 full-rate.
    {
      const float4* cb_ = (const float4*)&cfullf[kq * 128];
      v2f aA0 = {0.f, 0.f}, aA1 = {0.f, 0.f}, aB0 = {0.f, 0.f}, aB1 = {0.f, 0.f};
#pragma unroll
      for (int j = 0; j < 32; ++j) {
        float4 c4 = cb_[j];
        v2f c01; c01.x = c4.x; c01.y = c4.y;
        v2f c23; c23.x = c4.z; c23.y = c4.w;
        aA0 = __builtin_elementwise_fma(wAp[2 * j],     c01, aA0);
        aA1 = __builtin_elementwise_fma(wAp[2 * j + 1], c23, aA1);
        aB0 = __builtin_elementwise_fma(wBp[2 * j],     c01, aB0);
        aB1 = __builtin_elementwise_fma(wBp[2 * j + 1], c23, aB1);
      }
      float2 pv;
      pv.x = (aA0.x + aA0.y) + (aA1.x + aA1.y);
      pv.y = (aB0.x + aB0.y) + (aB1.x + aB1.y);
      part2[kq * 128 + hp] = pv;
    }

    __syncthreads();   // all part2 visible

    if (ft < 128u) {
      // finalize rows 2fp,2fp+1: sum 4 kq partials, +bias +e, tanh, pack
      float2 q0 = part2[fp];
      float2 q1 = part2[128 + fp];
      float2 q2 = part2[256 + fp];
      float2 q3 = part2[384 + fp];
      float s0 = ((q0.x + q1.x) + (q2.x + q3.x)) + biasv.x + bf2f(ep0 & 0xffffu);
      float s1 = ((q0.y + q1.y) + (q2.y + q3.y)) + biasv.y + bf2f(ep0 >> 16);
      float t0 = fast_tanh(s0), t1 = fast_tanh(s1);
      uint32_t pr = pk2(t0, t1);
      if (i != 511) {
        // publish FIRST (partner's poll is the critical consumer), then LDS
        uint64_t pkt = ((uint64_t)(uint32_t)(i + 1) << 32) | (uint64_t)pr;
        __hip_atomic_store(&cbuf[(size_t)(((i & 1) * 256 + bid) * 128 + fp)],
                           pkt, __ATOMIC_RELAXED, __HIP_MEMORY_SCOPE_AGENT);
        float2 cw; cw.x = t0; cw.y = t1;
        *(float2*)&cfullf[2 * (half * 128 + fp)] = cw;
        prPrev = pr; sPrev = s;
      } else {
        *(uint32_t*)&cat[(size_t)(s * BB + b) * KCAT + fcol] = pr;
      }
    }

    if (i == 511) break;
    __syncthreads();   // cfullf local half updated before next dot

    ep0 = ep1; ep1 = ep2;
  }
}

// ---------- K4: max-reduce partials, classifier, log_softmax ----------
__global__ __launch_bounds__(256) void final_kernel(
    const float* __restrict__ partial, const float* __restrict__ Wdoc,
    const float* __restrict__ bdoc, float* __restrict__ out)
{
  const int b = blockIdx.x, t = threadIdx.x;
  __shared__ float ym[1024];
  __shared__ float lg[32];
  float m0 = -2.f, m1 = -2.f, m2 = -2.f, m3 = -2.f;
  for (int mg = 0; mg < 256; ++mg) {
    const float* p = partial + ((size_t)mg * 64 + b) * 1024;
    m0 = fmaxf(m0, p[t]);
    m1 = fmaxf(m1, p[t + 256]);
    m2 = fmaxf(m2, p[t + 512]);
    m3 = fmaxf(m3, p[t + 768]);
  }
  ym[t] = m0; ym[t + 256] = m1; ym[t + 512] = m2; ym[t + 768] = m3;
  __syncthreads();
  if (t < NCLS) {
    const float* wr = Wdoc + (size_t)t * 1024;
    float a0 = 0.f, a1 = 0.f, a2 = 0.f, a3 = 0.f;
    for (int n = 0; n < 1024; n += 4) {
      a0 = fmaf(ym[n], wr[n], a0);
      a1 = fmaf(ym[n + 1], wr[n + 1], a1);
      a2 = fmaf(ym[n + 2], wr[n + 2], a2);
      a3 = fmaf(ym[n + 3], wr[n + 3], a3);
    }
    lg[t] = (a0 + a1) + (a2 + a3) + bdoc[t];
  }
  __syncthreads();
  if (t < NCLS) {
    float mx = -1e30f;
    for (int c = 0; c < NCLS; ++c) mx = fmaxf(mx, lg[c]);
    float ssum = 0.f;
    for (int c = 0; c < NCLS; ++c) ssum += expf(lg[c] - mx);
    out[b * NCLS + t] = lg[t] - mx - logf(ssum);
  }
}

// ---------- launch ----------
extern "C" void kernel_launch(void* const* d_in, const int* in_sizes, int n_in,
                              void* d_out, int out_size, void* d_ws, size_t ws_size,
                              hipStream_t stream) {
  const int*   inp   = (const int*)  d_in[0];
  const float* table = (const float*)d_in[1];
  const float* cl0   = (const float*)d_in[2];
  const float* cr0   = (const float*)d_in[3];
  const float* Wl    = (const float*)d_in[4];
  const float* bl    = (const float*)d_in[5];
  const float* Wr    = (const float*)d_in[6];
  const float* br    = (const float*)d_in[7];
  const float* Wsl   = (const float*)d_in[8];
  const float* bsl   = (const float*)d_in[9];
  const float* Wsr   = (const float*)d_in[10];
  const float* bsr   = (const float*)d_in[11];
  const float* Wmax  = (const float*)d_in[12];
  const float* bmax  = (const float*)d_in[13];
  const float* Wdoc  = (const float*)d_in[14];
  const float* bdoc  = (const float*)d_in[15];

  uint8_t* ws = (uint8_t*)d_ws;
  uint16_t* cat     = (uint16_t*)(ws);                 // 32768*1536*2 = 100663296
  uint16_t* ee      = (uint16_t*)(ws + 100663296);     // 32768*1024*2 = 67108864
  float*    partial = (float*)   (ws + 167772160);     // 256*64*1024*4 = 67108864
  uint16_t* wslb    = (uint16_t*)(ws + 234881024);     // 524288
  uint16_t* wsrb    = (uint16_t*)(ws + 235405312);     // 524288
  uint16_t* wmaxb   = (uint16_t*)(ws + 235929600);     // 3145728
  uint16_t* wlb     = (uint16_t*)(ws + 239075328);     // 524288
  uint16_t* wrb     = (uint16_t*)(ws + 239599616);     // 524288
  // cbuf (u64 seq|payload, 2 parity x 256 bid x 128 words = 512 KB) overlays the
  // START of `partial`: poisoned 0xAA at launch (seq never matches), and gemm<1>
  // fully overwrites partial AFTER the scan completes. No ws growth.
  uint64_t* cbuf    = (uint64_t*)(ws + 167772160);

  prep_kernel<<<9472, 256, 0, stream>>>(inp, table, Wsl, Wsr, Wl, Wr, Wmax,
                                        cat, wslb, wsrb, wlb, wrb, wmaxb);
  gemm_kernel<0><<<dim3(256, 8), 256, 0, stream>>>(cat + 512, KCAT, 512, wslb, wsrb,
                                                   bsl, bsr, ee, nullptr);
  scan_kernel<<<256, 512, 0, stream>>>(ee, wlb, wrb, bl, br, cl0, cr0, cat, cbuf);
  gemm_kernel<1><<<dim3(256, 8), 256, 0, stream>>>(cat, KCAT, KCAT, wmaxb, nullptr,
                                                   bmax, nullptr, nullptr, partial);
  final_kernel<<<64, 256, 0, stream>>>(partial, Wdoc, bdoc, (float*)d_out);
}

// Round 10
// 995.615 us; speedup vs baseline: 2.2528x; 2.2528x over previous
//
#include <hip/hip_runtime.h>
#include <hip/hip_bf16.h>
#include <cstdint>
#include <cstddef>

// Problem dims
#define SS   512
#define BB   64
#define EMBD 512
#define HIDD 512
#define MAXD 1024
#define NCLS 20
#define KCAT 1536
#define ROWS (SS*BB)   // 32768

// ---------- small helpers ----------
__device__ __forceinline__ uint16_t f2bf(float f) {
  uint32_t u = __float_as_uint(f);
  uint32_t r = u + 0x7fffu + ((u >> 16) & 1u);
  return (uint16_t)(r >> 16);
}
__device__ __forceinline__ float bf2f(uint32_t h) {
  return __uint_as_float(h << 16);
}
__device__ __forceinline__ uint32_t pk2(float a, float b) {
  return (uint32_t)f2bf(a) | ((uint32_t)f2bf(b) << 16);
}

// fast tanh: (1-e^{-2|x|})/(1+e^{-2|x|}) with native exp2/rcp, sign restore.
__device__ __forceinline__ float fast_tanh(float x) {
  float ax = __builtin_fabsf(x);
  float e  = __builtin_amdgcn_exp2f(ax * -2.885390081777927f);  // e^{-2ax}
  float r  = (1.f - e) * __builtin_amdgcn_rcpf(1.f + e);
  return __builtin_copysignf(r, x);
}

#if defined(__has_builtin)
#if __has_builtin(__builtin_amdgcn_fdot2_f32_bf16)
#define USE_BF16_DOT2 1
#endif
#endif

#ifdef USE_BF16_DOT2
typedef __bf16 bf16x2_t __attribute__((ext_vector_type(2)));
__device__ __forceinline__ float dot2bf(uint32_t w, uint32_t c, float acc) {
  return __builtin_amdgcn_fdot2_f32_bf16(__builtin_bit_cast(bf16x2_t, w),
                                         __builtin_bit_cast(bf16x2_t, c), acc, false);
}
#else
__device__ __forceinline__ float dot2bf(uint32_t w, uint32_t c, float acc) {
  float w0 = __uint_as_float(w << 16);
  float w1 = __uint_as_float(w & 0xffff0000u);
  float c0 = __uint_as_float(c << 16);
  float c1 = __uint_as_float(c & 0xffff0000u);
  return fmaf(w1, c1, fmaf(w0, c0, acc));
}
#endif

__device__ __forceinline__ void gl_lds16(const void* g, void* l) {
  __builtin_amdgcn_global_load_lds((const __attribute__((address_space(1))) void*)g,
                                   (__attribute__((address_space(3))) void*)l,
                                   16, 0, 0);
}

typedef short v8s __attribute__((ext_vector_type(8)));
typedef float v4f __attribute__((ext_vector_type(4)));

// ---------- K0: gather emb -> cat[:,512:1024] (bf16), convert weights to bf16 ----------
__global__ __launch_bounds__(256) void prep_kernel(
    const int* __restrict__ inp, const float* __restrict__ table,
    const float* __restrict__ Wsl, const float* __restrict__ Wsr,
    const float* __restrict__ Wl,  const float* __restrict__ Wr,
    const float* __restrict__ Wmax,
    uint16_t* __restrict__ cat, uint16_t* __restrict__ wslb,
    uint16_t* __restrict__ wsrb, uint16_t* __restrict__ wlb,
    uint16_t* __restrict__ wrb, uint16_t* __restrict__ wmaxb)
{
  const int blk = blockIdx.x, t = threadIdx.x;
  if (blk < 8192) {
    const int r = blk * 4 + (t >> 6);
    const int lane = t & 63;
    const int token = inp[r];
    const float4* src = (const float4*)(table + (size_t)token * EMBD);
    uint16_t* dst = cat + (size_t)r * KCAT + 512;
#pragma unroll
    for (int p = 0; p < 2; ++p) {
      const int slot = lane + 64 * p;   // 0..127 float4 slots per row
      float4 v = src[slot];
      uint2 o;
      o.x = pk2(v.x, v.y);
      o.y = pk2(v.z, v.w);
      *(uint2*)(dst + slot * 4) = o;
    }
  } else {
    size_t flat = (size_t)(blk - 8192) * 2048 + (size_t)t * 8;
    const float* src; uint16_t* dst; size_t off;
    if (flat < 262144)       { src = Wsl;  dst = wslb;  off = flat; }
    else if (flat < 524288)  { src = Wsr;  dst = wsrb;  off = flat - 262144; }
    else if (flat < 786432)  { src = Wl;   dst = wlb;   off = flat - 524288; }
    else if (flat < 1048576) { src = Wr;   dst = wrb;   off = flat - 786432; }
    else                     { src = Wmax; dst = wmaxb; off = flat - 1048576; }
    float4 v0 = *(const float4*)(src + off);
    float4 v1 = *(const float4*)(src + off + 4);
    uint4 o;
    o.x = pk2(v0.x, v0.y); o.y = pk2(v0.z, v0.w);
    o.z = pk2(v1.x, v1.y); o.w = pk2(v1.z, v1.w);
    *(uint4*)(dst + off) = o;
  }
}

// ---------- GEMM (m97-style): C[M x 1024] = A[M x K] @ W^T, 128x128 tiles, BK=64 ----------
// MODE 0: out = A@W^T + bias -> bf16 store (proj GEMM, W split at n=512)
// MODE 1: v = tanh(A@W^T + bias); partial[mb][b][n] = max over the block's 2 s-rows
template<int MODE>
__global__ __launch_bounds__(256, 2) void gemm_kernel(
    const uint16_t* __restrict__ A, int lda, int K,
    const uint16_t* __restrict__ W0, const uint16_t* __restrict__ W1,
    const float* __restrict__ bias0, const float* __restrict__ bias1,
    uint16_t* __restrict__ outb, float* __restrict__ partial)
{
  __shared__ unsigned char smem[32768];
  uint16_t* lA = (uint16_t*)smem;            // 128x64 bf16 = 16 KB
  uint16_t* lW = (uint16_t*)(smem + 16384);  // 128x64 bf16 = 16 KB

  const int tid = threadIdx.x;
  const int mb = blockIdx.x, nb = blockIdx.y;
  const int m0 = mb * 128, n0 = nb * 128;

  const uint16_t* Wp = W0;
  const float* biasp = bias0;
  int nr0 = n0;
  if (MODE == 0 && n0 >= 512) { Wp = W1; biasp = bias1; nr0 = n0 - 512; }

  const int w = tid >> 6, lane = tid & 63;
  const int mw = w & 1, nw = w >> 1;

  v4f acc[4][4];
#pragma unroll
  for (int i = 0; i < 4; ++i)
#pragma unroll
    for (int j = 0; j < 4; ++j) {
      v4f z = {0.f, 0.f, 0.f, 0.f};
      acc[i][j] = z;
    }

  const int r_st = tid >> 3;   // + p*32
  const int u_st = tid & 7;

  for (int kk = 0; kk < K; kk += 64) {
    __syncthreads();
#pragma unroll
    for (int p = 0; p < 4; ++p) {
      const int r = p * 32 + r_st;
      gl_lds16(A + (size_t)(m0 + r) * lda + kk + u_st * 8, lA + (p * 256 + tid) * 8);
    }
#pragma unroll
    for (int p = 0; p < 4; ++p) {
      const int r = p * 32 + r_st;
      gl_lds16(Wp + (size_t)(nr0 + r) * K + kk + u_st * 8, lW + (p * 256 + tid) * 8);
    }
    __syncthreads();
#pragma unroll
    for (int ks = 0; ks < 2; ++ks) {
      v8s af[4], wf[4];
#pragma unroll
      for (int i = 0; i < 4; ++i)
        af[i] = *(const v8s*)&lA[(mw * 64 + i * 16 + (lane & 15)) * 64 + ks * 32 + (lane >> 4) * 8];
#pragma unroll
      for (int j = 0; j < 4; ++j)
        wf[j] = *(const v8s*)&lW[(nw * 64 + j * 16 + (lane & 15)) * 64 + ks * 32 + (lane >> 4) * 8];
#pragma unroll
      for (int i = 0; i < 4; ++i)
#pragma unroll
        for (int j = 0; j < 4; ++j)
          acc[i][j] = __builtin_amdgcn_mfma_f32_16x16x32_bf16(af[i], wf[j], acc[i][j], 0, 0, 0);
    }
  }

  __syncthreads();  // all LDS frag reads done before epilogue reuse

  if (MODE == 0) {
#pragma unroll
    for (int i = 0; i < 4; ++i)
#pragma unroll
      for (int j = 0; j < 4; ++j) {
        const int nl = nw * 64 + j * 16 + (lane & 15);
        const float bv = biasp[nr0 + nl];
        const int colg = n0 + nl;
#pragma unroll
        for (int r = 0; r < 4; ++r) {
          const int rowg = m0 + mw * 64 + i * 16 + (lane >> 4) * 4 + r;
          outb[(size_t)rowg * 1024 + colg] = f2bf(acc[i][j][r] + bv);
        }
      }
  } else {
    float* lred = (float*)smem;   // 64 b x 128 n f32 = 32 KB
    if (mw == 1) {
#pragma unroll
      for (int i = 0; i < 4; ++i)
#pragma unroll
        for (int j = 0; j < 4; ++j) {
          const int nl = nw * 64 + j * 16 + (lane & 15);
          const float bv = biasp[nr0 + nl];
#pragma unroll
          for (int r = 0; r < 4; ++r) {
            const int bl = i * 16 + (lane >> 4) * 4 + r;
            lred[bl * 128 + nl] = fast_tanh(acc[i][j][r] + bv);
          }
        }
    }
    __syncthreads();
    if (mw == 0) {
#pragma unroll
      for (int i = 0; i < 4; ++i)
#pragma unroll
        for (int j = 0; j < 4; ++j) {
          const int nl = nw * 64 + j * 16 + (lane & 15);
          const float bv = biasp[nr0 + nl];
#pragma unroll
          for (int r = 0; r < 4; ++r) {
            const int bl = i * 16 + (lane >> 4) * 4 + r;
            const float v = fast_tanh(acc[i][j][r] + bv);
            partial[((size_t)mb * 64 + bl) * 1024 + n0 + nl] = fmaxf(v, lred[bl * 128 + nl]);
          }
        }
    }
  }
}

// ---------- K2: bidirectional recurrence, exchange-overlapped-with-local-dot ----------
// FINAL: this is the session-best R3 structure (scan ~643us, total ~995us).
// All six structural alternatives regressed: readlane dot (678), single-barrier
// quad (1019), poll-in-finalize-window (846), MFMA scan (1460), packed-f32 dot
// (1945, register spill). The step is latency-bound on the serial 512-step
// recurrence: ~1024cyc dot2 issue + ~240 finalize + ~1750 barrier-convergence/
// poll-residual. Key balance points of this structure:
//  * 256 blocks x 512 threads: block = (h-half, dir d, batch b); partner =
//    bid^128 (same bid%8 -> same XCD L2).
//  * W bf16 register-resident (parks in unified AGPR file, free).
//  * local waves (k-window in own c-half) dot immediately post-barrier; remote
//    waves poll seq=i (published a full dot earlier, visible by now) then
//    ds_write + lgkmcnt + dot -- the L2 round trip hides under the local dot
//    on the same SIMD (1 local + 1 remote wave per SIMD).
//  * publish FIRST in finalize (partner's poll is the critical consumer).
//  * u64 seq|payload packets, parity double-buffer; skew <=1 proven.
__global__ __launch_bounds__(512, 1) void scan_kernel(
    const uint16_t* __restrict__ ee,     // [32768][1024] bf16: ls | rs
    const uint16_t* __restrict__ wlb, const uint16_t* __restrict__ wrb,
    const float* __restrict__ bl, const float* __restrict__ br,
    const float* __restrict__ cl0, const float* __restrict__ cr0,
    uint16_t* __restrict__ cat,
    uint64_t* __restrict__ cbuf)
{
  const int tid = threadIdx.x;
  const int bid = blockIdx.x;
  const int b    = bid & 63;
  const int d    = (bid >> 6) & 1;
  const int half = bid >> 7;          // h-half; partner differs only in bit 7

  // dot geometry: hp = row-pair within half (rows half*256+2hp, +1),
  // kq = 128-element k-window = 64 u32 words of cfull.
  const int hp = tid & 127;
  const int kq = tid >> 7;            // wave-uniform
  const bool remote = (kq >> 1) != half;   // wave's k-window is the partner's half

  __shared__ __align__(16) uint32_t cfull[256];   // full c (512 h) as bf16-pairs
  __shared__ float2 part2[4 * 128];               // [kq][hp] = (rowEven, rowOdd)

  // ---- W rows into VGPRs/AGPRs (loop-invariant; 32 uint4) ----
  uint4 wA[16], wB[16];
  {
    const uint16_t* wsrc = (d ? wrb : wlb) + (size_t)(half * 256 + 2 * hp) * HIDD + kq * 128;
    const uint4* pA = (const uint4*)wsrc;
    const uint4* pB = (const uint4*)(wsrc + HIDD);
#pragma unroll
    for (int j = 0; j < 16; ++j) { wA[j] = pA[j]; wB[j] = pB[j]; }
  }
  if (tid < 256) {
    const float* c0v = d ? cr0 : cl0;
    float2 cv = ((const float2*)c0v)[tid];
    cfull[tid] = pk2(cv.x, cv.y);
  }

  // finalize lanes: 2 local waves -> tid in [half*256, half*256+128)
  const int fbase = half * 256;
  const unsigned ft = (unsigned)(tid - fbase);   // <128u => finalize lane
  const int fp = tid - fbase;

  float2 biasv = {0.f, 0.f};
  if (ft < 128u) {
    const float* bvec = d ? br : bl;
    biasv = ((const float2*)bvec)[half * 128 + fp];
  }
  __syncthreads();

  const size_t ecol = (size_t)(d * 512 + half * 256 + 2 * fp);
  const int fcol = (d ? 1024 : 0) + half * 256 + 2 * fp;   // cat column

  // remote-wave poll geometry: slot j in partner's publish block <-> our cfull
  // word (1-half)*128 + j; this wave needs exactly words [kq*64, kq*64+64).
  const int pslot = ((kq & 1) << 6) | (tid & 63);
  const int cword = ((1 - half) << 7) | pslot;
  const int pbid  = bid ^ 128;

  // 2-deep ee prefetch ring (finalize lanes)
  uint32_t ep0 = 0, ep1 = 0;
  if (ft < 128u) {
    const int s0i = d ? 511 : 0;
    const int s1i = d ? 510 : 1;
    ep0 = *(const uint32_t*)&ee[(size_t)(s0i * BB + b) * 1024 + ecol];
    ep1 = *(const uint32_t*)&ee[(size_t)(s1i * BB + b) * 1024 + ecol];
  }

  uint32_t prPrev = 0;
  int sPrev = -1;

  for (int i = 0; i < 512; ++i) {
    const int s = d ? (511 - i) : i;
    uint32_t ep2 = 0;
    if (ft < 128u) {
      const int i2 = (i + 2) & 511;
      const int s2 = d ? (511 - i2) : i2;
      ep2 = *(const uint32_t*)&ee[(size_t)(s2 * BB + b) * 1024 + ecol];
      // pipelined cat store from previous iteration (drains during the dot)
      if (sPrev >= 0)
        *(uint32_t*)&cat[(size_t)(sPrev * BB + b) * KCAT + fcol] = prPrev;
    }

    // remote waves: fetch the partner c-half words this wave's dot needs.
    // seq i was published by partner at its iter i-1 (parity (i&1)^1).
    if (remote && i != 0) {
      const uint64_t want = (uint64_t)(uint32_t)i;
      const uint64_t* slot = &cbuf[(size_t)(((((i & 1) ^ 1)) * 256 + pbid) * 128 + pslot)];
      uint64_t v = __hip_atomic_load(slot, __ATOMIC_RELAXED, __HIP_MEMORY_SCOPE_AGENT);
      while ((v >> 32) != want) {
        __builtin_amdgcn_s_sleep(1);
        v = __hip_atomic_load(slot, __ATOMIC_RELAXED, __HIP_MEMORY_SCOPE_AGENT);
      }
      cfull[cword] = (uint32_t)v;
      // wave-local: our 64 lanes wrote exactly the 64 words we are about to read.
      // Force ds_write completion before the dot's ds_reads (cross-lane dep the
      // compiler can't see). "memory" clobber orders the following LDS reads.
      asm volatile("s_waitcnt lgkmcnt(0)" ::: "memory");
    }

    // dot: rows half*256+2hp/+1, k-window [kq*128,+128). W in regs; c reads are
    // wave-uniform ds_read_b128 broadcasts (16 per thread).
    {
      const uint32_t* cb_ = &cfull[kq * 64];
      float a0 = 0.f, a1 = 0.f, a2 = 0.f, a3 = 0.f;
#pragma unroll
      for (int j = 0; j < 16; ++j) {
        uint4 c4 = *(const uint4*)(cb_ + j * 4);
        a0 = dot2bf(wA[j].x, c4.x, a0); a2 = dot2bf(wA[j].y, c4.y, a2);
        a1 = dot2bf(wB[j].x, c4.x, a1); a3 = dot2bf(wB[j].y, c4.y, a3);
        a0 = dot2bf(wA[j].z, c4.z, a0); a2 = dot2bf(wA[j].w, c4.w, a2);
        a1 = dot2bf(wB[j].z, c4.z, a1); a3 = dot2bf(wB[j].w, c4.w, a3);
      }
      float2 pv; pv.x = a0 + a2; pv.y = a1 + a3;
      part2[kq * 128 + hp] = pv;
    }

    __syncthreads();   // all part2 visible

    if (ft < 128u) {
      // finalize rows 2fp,2fp+1: sum 4 kq partials, +bias +e, tanh, pack
      float2 q0 = part2[fp];
      float2 q1 = part2[128 + fp];
      float2 q2 = part2[256 + fp];
      float2 q3 = part2[384 + fp];
      float s0 = ((q0.x + q1.x) + (q2.x + q3.x)) + biasv.x + bf2f(ep0 & 0xffffu);
      float s1 = ((q0.y + q1.y) + (q2.y + q3.y)) + biasv.y + bf2f(ep0 >> 16);
      uint32_t pr = pk2(fast_tanh(s0), fast_tanh(s1));
      if (i != 511) {
        // publish FIRST (partner's poll is the critical consumer), then LDS
        uint64_t pkt = ((uint64_t)(uint32_t)(i + 1) << 32) | (uint64_t)pr;
        __hip_atomic_store(&cbuf[(size_t)(((i & 1) * 256 + bid) * 128 + fp)],
                           pkt, __ATOMIC_RELAXED, __HIP_MEMORY_SCOPE_AGENT);
        cfull[half * 128 + fp] = pr;
        prPrev = pr; sPrev = s;
      } else {
        *(uint32_t*)&cat[(size_t)(s * BB + b) * KCAT + fcol] = pr;
      }
    }

    if (i == 511) break;
    __syncthreads();   // cfull local half updated before next dot

    ep0 = ep1; ep1 = ep2;
  }
}

// ---------- K4: max-reduce partials, classifier, log_softmax ----------
__global__ __launch_bounds__(256) void final_kernel(
    const float* __restrict__ partial, const float* __restrict__ Wdoc,
    const float* __restrict__ bdoc, float* __restrict__ out)
{
  const int b = blockIdx.x, t = threadIdx.x;
  __shared__ float ym[1024];
  __shared__ float lg[32];
  float m0 = -2.f, m1 = -2.f, m2 = -2.f, m3 = -2.f;
  for (int mg = 0; mg < 256; ++mg) {
    const float* p = partial + ((size_t)mg * 64 + b) * 1024;
    m0 = fmaxf(m0, p[t]);
    m1 = fmaxf(m1, p[t + 256]);
    m2 = fmaxf(m2, p[t + 512]);
    m3 = fmaxf(m3, p[t + 768]);
  }
  ym[t] = m0; ym[t + 256] = m1; ym[t + 512] = m2; ym[t + 768] = m3;
  __syncthreads();
  if (t < NCLS) {
    const float* wr = Wdoc + (size_t)t * 1024;
    float a0 = 0.f, a1 = 0.f, a2 = 0.f, a3 = 0.f;
    for (int n = 0; n < 1024; n += 4) {
      a0 = fmaf(ym[n], wr[n], a0);
      a1 = fmaf(ym[n + 1], wr[n + 1], a1);
      a2 = fmaf(ym[n + 2], wr[n + 2], a2);
      a3 = fmaf(ym[n + 3], wr[n + 3], a3);
    }
    lg[t] = (a0 + a1) + (a2 + a3) + bdoc[t];
  }
  __syncthreads();
  if (t < NCLS) {
    float mx = -1e30f;
    for (int c = 0; c < NCLS; ++c) mx = fmaxf(mx, lg[c]);
    float ssum = 0.f;
    for (int c = 0; c < NCLS; ++c) ssum += expf(lg[c] - mx);
    out[b * NCLS + t] = lg[t] - mx - logf(ssum);
  }
}

// ---------- launch ----------
extern "C" void kernel_launch(void* const* d_in, const int* in_sizes, int n_in,
                              void* d_out, int out_size, void* d_ws, size_t ws_size,
                              hipStream_t stream) {
  const int*   inp   = (const int*)  d_in[0];
  const float* table = (const float*)d_in[1];
  const float* cl0   = (const float*)d_in[2];
  const float* cr0   = (const float*)d_in[3];
  const float* Wl    = (const float*)d_in[4];
  const float* bl    = (const float*)d_in[5];
  const float* Wr    = (const float*)d_in[6];
  const float* br    = (const float*)d_in[7];
  const float* Wsl   = (const float*)d_in[8];
  const float* bsl   = (const float*)d_in[9];
  const float* Wsr   = (const float*)d_in[10];
  const float* bsr   = (const float*)d_in[11];
  const float* Wmax  = (const float*)d_in[12];
  const float* bmax  = (const float*)d_in[13];
  const float* Wdoc  = (const float*)d_in[14];
  const float* bdoc  = (const float*)d_in[15];

  uint8_t* ws = (uint8_t*)d_ws;
  uint16_t* cat     = (uint16_t*)(ws);                 // 32768*1536*2 = 100663296
  uint16_t* ee      = (uint16_t*)(ws + 100663296);     // 32768*1024*2 = 67108864
  float*    partial = (float*)   (ws + 167772160);     // 256*64*1024*4 = 67108864
  uint16_t* wslb    = (uint16_t*)(ws + 234881024);     // 524288
  uint16_t* wsrb    = (uint16_t*)(ws + 235405312);     // 524288
  uint16_t* wmaxb   = (uint16_t*)(ws + 235929600);     // 3145728
  uint16_t* wlb     = (uint16_t*)(ws + 239075328);     // 524288
  uint16_t* wrb     = (uint16_t*)(ws + 239599616);     // 524288
  // cbuf (u64 seq|payload, 2 parity x 256 bid x 128 words = 512 KB) overlays the
  // START of `partial`: poisoned 0xAA at launch (seq never matches), and gemm<1>
  // fully overwrites partial AFTER the scan completes. No ws growth.
  uint64_t* cbuf    = (uint64_t*)(ws + 167772160);

  prep_kernel<<<9472, 256, 0, stream>>>(inp, table, Wsl, Wsr, Wl, Wr, Wmax,
                                        cat, wslb, wsrb, wlb, wrb, wmaxb);
  gemm_kernel<0><<<dim3(256, 8), 256, 0, stream>>>(cat + 512, KCAT, 512, wslb, wsrb,
                                                   bsl, bsr, ee, nullptr);
  scan_kernel<<<256, 512, 0, stream>>>(ee, wlb, wrb, bl, br, cl0, cr0, cat, cbuf);
  gemm_kernel<1><<<dim3(256, 8), 256, 0, stream>>>(cat, KCAT, KCAT, wmaxb, nullptr,
                                                   bmax, nullptr, nullptr, partial);
  final_kernel<<<64, 256, 0, stream>>>(partial, Wdoc, bdoc, (float*)d_out);
}